// Round 1
// baseline (764.318 us; speedup 1.0000x reference)
//
#include <hip/hip_runtime.h>
#include <hip/hip_bf16.h>

// FeCAM scoring: scores[b,c] = -diff[c,b,:] @ Minv[c] @ diff[c,b,:]^T
// diff[c,b,e] = (x[b,e] - mean[c,e]) / diag[c,e]
// B=32, C=256, D=768.  Memory-bound: Minv = 604 MB read once (~96 us floor).
//
// Formulation: dist[b] = sum_d diff[b,d] * (sum_e M[d,e] * diff[b,e])
//  -> split over M rows d: grid = (6 chunks of 128 rows) x (256 classes).
//  MFMA v = M @ diff^T : A = M rows (streamed global->reg in A-frag layout),
//  B = diff^T (bf16 in LDS), D accumulates v[d,b]; epilogue dots with diff[b,d].

#define BATCH 32
#define NCLS 256
#define DIM 768
#define CHUNK 128              // M rows per block
#define NCHUNK (DIM / CHUNK)   // 6
#define PADW (DIM + 8)         // diff row stride in shorts: 776*2=1552 B, 16B-aligned,
                               // 388 words % 32 = 4 -> 2-way bank alias (free)

typedef __attribute__((ext_vector_type(8))) short bf16x8;
typedef __attribute__((ext_vector_type(4))) float f32x4;

__device__ __forceinline__ unsigned short f2bf(float f) {
    union { float f; unsigned u; } v; v.f = f;
    unsigned r = v.u + 0x7FFF + ((v.u >> 16) & 1);   // round-nearest-even
    return (unsigned short)(r >> 16);
}
__device__ __forceinline__ float bf2f(unsigned short u) {
    union { unsigned u; float f; } v; v.u = ((unsigned)u) << 16;
    return v.f;
}

__global__ __launch_bounds__(256, 3) void fecam_kernel(
    const float* __restrict__ x,      // [32, 768]
    const float* __restrict__ means,  // [256, 768]
    const float* __restrict__ diags,  // [256, 768]
    const float* __restrict__ Minv,   // [256, 768, 768]
    float* __restrict__ out)          // [32, 256] (pre-zeroed)
{
    __shared__ unsigned short diff[BATCH][PADW];   // bf16 diff, ~49.7 KB
    __shared__ float dist[BATCH];

    const int chunk = blockIdx.x;   // 0..5
    const int c     = blockIdx.y;   // 0..255
    const int tid   = threadIdx.x;  // 0..255

    if (tid < BATCH) dist[tid] = 0.f;

    // ---- compute diff[b][e] = (x[b,e] - mean[c,e]) / diag[c,e]  (bf16) ----
    for (int e = tid; e < DIM; e += 256) {          // 3 iters
        float mv = means[c * DIM + e];
        float dv = diags[c * DIM + e];
        float rdv = 1.0f / dv;
        #pragma unroll 8
        for (int b = 0; b < BATCH; ++b) {
            diff[b][e] = f2bf((x[b * DIM + e] - mv) * rdv);
        }
    }
    __syncthreads();

    // ---- main: stream M rows, MFMA v[d,b] = sum_e M[d,e] diff[b,e] ----
    const int wave = tid >> 6;
    const int lane = tid & 63;
    const int l15  = lane & 15;
    const int quad = lane >> 4;

    const float* Mc = Minv + (size_t)c * DIM * DIM;

    for (int t = 0; t < 2; ++t) {
        const int d0 = chunk * CHUNK + (wave * 2 + t) * 16;   // m-tile base row
        // A-frag layout (16x16x32 bf16, HW-verified): A[m=lane&15][k=quad*8+j]
        const float* rowp = Mc + (size_t)(d0 + l15) * DIM + quad * 8;

        f32x4 acc0 = {0.f, 0.f, 0.f, 0.f};
        f32x4 acc1 = {0.f, 0.f, 0.f, 0.f};

        // software pipeline: preload k-step 0 (2 x dwordx4 per lane)
        float4 la = *(const float4*)(rowp);
        float4 lb = *(const float4*)(rowp + 4);

        for (int kb = 0; kb < DIM; kb += 32) {
            bf16x8 afrag;
            afrag[0] = (short)f2bf(la.x); afrag[1] = (short)f2bf(la.y);
            afrag[2] = (short)f2bf(la.z); afrag[3] = (short)f2bf(la.w);
            afrag[4] = (short)f2bf(lb.x); afrag[5] = (short)f2bf(lb.y);
            afrag[6] = (short)f2bf(lb.z); afrag[7] = (short)f2bf(lb.w);

            if (kb + 32 < DIM) {                 // preload next k-step
                rowp += 32;
                la = *(const float4*)(rowp);
                lb = *(const float4*)(rowp + 4);
            }

            // B-frag: B[k=quad*8+j][n=lane&15] = diff[n][kb+quad*8+j]
            bf16x8 b0 = *(const bf16x8*)&diff[l15][kb + quad * 8];
            bf16x8 b1 = *(const bf16x8*)&diff[16 + l15][kb + quad * 8];

            acc0 = __builtin_amdgcn_mfma_f32_16x16x32_bf16(afrag, b0, acc0, 0, 0, 0);
            acc1 = __builtin_amdgcn_mfma_f32_16x16x32_bf16(afrag, b1, acc1, 0, 0, 0);
        }

        // ---- epilogue: dist[b] += sum_d diff[b,d] * v[d,b] ----
        // C/D layout: col(n=b) = lane&15, row(m=d offset) = quad*4 + reg
        #pragma unroll
        for (int nt = 0; nt < 2; ++nt) {
            f32x4 acc = nt ? acc1 : acc0;
            const int b = nt * 16 + l15;
            float s = 0.f;
            #pragma unroll
            for (int r = 0; r < 4; ++r) {
                const int d = d0 + quad * 4 + r;
                s += acc[r] * bf2f(diff[b][d]);
            }
            s += __shfl_xor(s, 16);
            s += __shfl_xor(s, 32);
            if (lane < 16) atomicAdd(&dist[b], s);
        }
    }

    __syncthreads();
    if (tid < BATCH) atomicAdd(&out[tid * NCLS + c], -dist[tid]);
}

extern "C" void kernel_launch(void* const* d_in, const int* in_sizes, int n_in,
                              void* d_out, int out_size, void* d_ws, size_t ws_size,
                              hipStream_t stream) {
    const float* x     = (const float*)d_in[0];   // raw_features [32,768]
    const float* means = (const float*)d_in[1];   // class_means  [256,768]
    const float* diags = (const float*)d_in[2];   // class_diags  [256,768]
    const float* Minv  = (const float*)d_in[3];   // class_cov_invs [256,768,768]
    float* out = (float*)d_out;                   // [32,256] fp32

    hipMemsetAsync(out, 0, (size_t)BATCH * NCLS * sizeof(float), stream);

    dim3 grid(NCHUNK, NCLS);
    fecam_kernel<<<grid, 256, 0, stream>>>(x, means, diags, Minv, out);
}

// Round 3
// 760.568 us; speedup vs baseline: 1.0049x; 1.0049x over previous
//
#include <hip/hip_runtime.h>
#include <hip/hip_bf16.h>

// FeCAM scoring: scores[b,c] = -diff[c,b,:] @ Minv[c] @ diff[c,b,:]^T
// diff[c,b,e] = (x[b,e] - mean[c,e]) / diag[c,e];  B=32, C=256, D=768.
// Memory-bound: Minv = 604 MB fp32 read exactly once -> ~100 us floor at 6.3 TB/s.
//
// dist[b] = sum_d diff[b,d] * (sum_e M[d,e] * diff[b,e])  -> split over M rows.
// Grid = (3 chunks of 256 rows) x (256 classes) = 768 blocks (1 round on 256 CUs).
// Block = 512 threads (8 waves); wave w owns rows d0 = chunk*256 + w*32 .. +32.
// MFMA v = M @ diff^T: A = M rows streamed global->reg in A-frag layout
// (nontemporal, 2-stage prefetch, 2 row-tiles fused so LDS b-frags are shared),
// B = bf16 diff^T in LDS. Epilogue dots v[d,b] with diff[b,d], reduces.

#define BATCH 32
#define NCLS 256
#define DIM 768
#define CHUNK 256              // M rows per block
#define NCHUNK (DIM / CHUNK)   // 3
#define NTHREADS 512
#define PADW (DIM + 8)         // 776 shorts = 1552 B row stride; 388 words %32 = 4
                               // -> 2-way bank alias on ds_read_b128 (free per m136)

typedef __attribute__((ext_vector_type(8))) short bf16x8;
typedef __attribute__((ext_vector_type(4))) float f32x4;   // native vec for MFMA acc + NT loads

__device__ __forceinline__ unsigned short f2bf(float f) {
    union { float f; unsigned u; } v; v.f = f;
    unsigned r = v.u + 0x7FFF + ((v.u >> 16) & 1);   // round-nearest-even
    return (unsigned short)(r >> 16);
}
__device__ __forceinline__ float bf2f(unsigned short u) {
    union { unsigned u; float f; } v; v.u = ((unsigned)u) << 16;
    return v.f;
}
__device__ __forceinline__ f32x4 ntload(const float* p) {
    return __builtin_nontemporal_load((const f32x4*)p);   // M is stream-once
}
__device__ __forceinline__ void cvt8(const f32x4& a, const f32x4& b, bf16x8& o) {
    o[0] = (short)f2bf(a[0]); o[1] = (short)f2bf(a[1]);
    o[2] = (short)f2bf(a[2]); o[3] = (short)f2bf(a[3]);
    o[4] = (short)f2bf(b[0]); o[5] = (short)f2bf(b[1]);
    o[6] = (short)f2bf(b[2]); o[7] = (short)f2bf(b[3]);
}

__global__ __launch_bounds__(NTHREADS, 4) void fecam_kernel(
    const float* __restrict__ x,      // [32, 768]
    const float* __restrict__ means,  // [256, 768]
    const float* __restrict__ diags,  // [256, 768]
    const float* __restrict__ Minv,   // [256, 768, 768]
    float* __restrict__ out)          // [32, 256] (pre-zeroed)
{
    __shared__ unsigned short diff[BATCH][PADW];   // bf16 diff, ~49.7 KB
    __shared__ float dist[BATCH];

    const int chunk = blockIdx.x;   // 0..2
    const int c     = blockIdx.y;   // 0..255
    const int tid   = threadIdx.x;  // 0..511

    if (tid < BATCH) dist[tid] = 0.f;

    // ---- diff[b][e] = (x[b,e] - mean[c,e]) / diag[c,e]  (bf16 in LDS) ----
    for (int e = tid; e < DIM; e += NTHREADS) {
        float mv  = means[c * DIM + e];
        float rdv = 1.0f / diags[c * DIM + e];
        #pragma unroll 8
        for (int b = 0; b < BATCH; ++b)
            diff[b][e] = f2bf((x[b * DIM + e] - mv) * rdv);
    }
    __syncthreads();

    // ---- main: stream M rows, MFMA v[d,b] = sum_e M[d,e] diff[b,e] ----
    const int wave = tid >> 6;      // 0..7
    const int lane = tid & 63;
    const int l15  = lane & 15;
    const int quad = lane >> 4;

    const int d0 = chunk * CHUNK + wave * 32;   // this wave's 32 rows
    // A-frag layout (16x16x32 bf16, HW-verified): A[m=lane&15][k=quad*8+j]
    const float* row0 = Minv + (size_t)c * DIM * DIM + (size_t)(d0 + l15) * DIM + quad * 8;
    const float* row1 = row0 + 16 * DIM;        // second 16-row tile

    f32x4 acc00 = {0.f,0.f,0.f,0.f};   // tile0 x batch[0:16)
    f32x4 acc01 = {0.f,0.f,0.f,0.f};   // tile0 x batch[16:32)
    f32x4 acc10 = {0.f,0.f,0.f,0.f};   // tile1 x batch[0:16)
    f32x4 acc11 = {0.f,0.f,0.f,0.f};   // tile1 x batch[16:32)

    // 2-stage prefetch: stage S covers columns kb (S=0) / kb+32 (S=1)
    f32x4 pf[2][4];
    pf[0][0] = ntload(row0);      pf[0][1] = ntload(row0 + 4);
    pf[0][2] = ntload(row1);      pf[0][3] = ntload(row1 + 4);
    pf[1][0] = ntload(row0 + 32); pf[1][1] = ntload(row0 + 36);
    pf[1][2] = ntload(row1 + 32); pf[1][3] = ntload(row1 + 36);

#define KSTEP(S, KB)                                                          \
    {                                                                         \
        bf16x8 a0, a1;                                                        \
        cvt8(pf[S][0], pf[S][1], a0);                                         \
        cvt8(pf[S][2], pf[S][3], a1);                                         \
        if ((KB) + 64 < DIM) {                                                \
            pf[S][0] = ntload(row0 + (KB) + 64);                              \
            pf[S][1] = ntload(row0 + (KB) + 68);                              \
            pf[S][2] = ntload(row1 + (KB) + 64);                              \
            pf[S][3] = ntload(row1 + (KB) + 68);                              \
        }                                                                     \
        /* B-frag: B[k=quad*8+j][n=lane&15] = diff[n][KB+quad*8+j] */         \
        bf16x8 b0 = *(const bf16x8*)&diff[l15][(KB) + quad * 8];              \
        bf16x8 b1 = *(const bf16x8*)&diff[16 + l15][(KB) + quad * 8];         \
        acc00 = __builtin_amdgcn_mfma_f32_16x16x32_bf16(a0, b0, acc00, 0,0,0);\
        acc01 = __builtin_amdgcn_mfma_f32_16x16x32_bf16(a0, b1, acc01, 0,0,0);\
        acc10 = __builtin_amdgcn_mfma_f32_16x16x32_bf16(a1, b0, acc10, 0,0,0);\
        acc11 = __builtin_amdgcn_mfma_f32_16x16x32_bf16(a1, b1, acc11, 0,0,0);\
    }

    #pragma unroll
    for (int kb = 0; kb < DIM; kb += 64) {   // 12 iterations, fully unrolled
        KSTEP(0, kb);
        KSTEP(1, kb + 32);
    }
#undef KSTEP

    // ---- epilogue: dist[b] += sum_d diff[b,d] * v[d,b] ----
    // C/D layout: col(n=b) = lane&15, row(m) = quad*4 + reg
    float s0 = 0.f, s1 = 0.f;    // b = l15 and b = 16+l15
    #pragma unroll
    for (int r = 0; r < 4; ++r) {
        const int dA = d0 + quad * 4 + r;        // tile0 row
        const int dB = dA + 16;                  // tile1 row
        s0 += acc00[r] * bf2f(diff[l15][dA]);
        s0 += acc10[r] * bf2f(diff[l15][dB]);
        s1 += acc01[r] * bf2f(diff[16 + l15][dA]);
        s1 += acc11[r] * bf2f(diff[16 + l15][dB]);
    }
    s0 += __shfl_xor(s0, 16); s0 += __shfl_xor(s0, 32);
    s1 += __shfl_xor(s1, 16); s1 += __shfl_xor(s1, 32);
    if (lane < 16) {
        atomicAdd(&dist[l15], s0);
        atomicAdd(&dist[16 + l15], s1);
    }

    __syncthreads();
    if (tid < BATCH) atomicAdd(&out[tid * NCLS + c], -dist[tid]);
}

extern "C" void kernel_launch(void* const* d_in, const int* in_sizes, int n_in,
                              void* d_out, int out_size, void* d_ws, size_t ws_size,
                              hipStream_t stream) {
    const float* x     = (const float*)d_in[0];   // raw_features [32,768]
    const float* means = (const float*)d_in[1];   // class_means  [256,768]
    const float* diags = (const float*)d_in[2];   // class_diags  [256,768]
    const float* Minv  = (const float*)d_in[3];   // class_cov_invs [256,768,768]
    float* out = (float*)d_out;                   // [32,256] fp32

    (void)hipMemsetAsync(out, 0, (size_t)BATCH * NCLS * sizeof(float), stream);

    dim3 grid(NCHUNK, NCLS);
    fecam_kernel<<<grid, NTHREADS, 0, stream>>>(x, means, diags, Minv, out);
}